// Round 14
// baseline (173.961 us; speedup 1.0000x reference)
//
#include <hip/hip_runtime.h>
#include <hip/hip_bf16.h>
#include <math.h>

// Problem constants
#define GH 64
#define GW 64
#define CC 384
#define NHD 6
#define KW 7
#define DH 64
#define NTOK (GH*GW)          // 4096
#define LN_EPS 1e-6f

typedef __attribute__((ext_vector_type(4))) float f32x4;
typedef __attribute__((ext_vector_type(8))) short bf16x8;
typedef __hip_bfloat16 bf16;

typedef const __attribute__((address_space(1))) unsigned int* gptr_t;
typedef __attribute__((address_space(3))) unsigned int* lptr_t;

__device__ __forceinline__ float bf2f(unsigned int u16) {
    union { unsigned int i; float f; } c; c.i = u16 << 16; return c.f;
}
__device__ __forceinline__ bf16 f2bf(float f) { return __float2bfloat16(f); }

// ---------------------------------------------------------------------------
// Kernel 1: fused {4 weight transposes (64x64, vectorized)} + {ada} +
// {zero the proj/LN band counters}.
// ---------------------------------------------------------------------------
__global__ __launch_bounds__(256) void wt_ada_k(const float* __restrict__ qkv_w,
                                                const float* __restrict__ proj_w,
                                                const float* __restrict__ fc1_w,
                                                const float* __restrict__ fc2_w,
                                                bf16* __restrict__ qkv_wt,
                                                bf16* __restrict__ proj_wt,
                                                bf16* __restrict__ fc1_wt,
                                                bf16* __restrict__ fc2_wt,
                                                const float* __restrict__ cond,
                                                const float* __restrict__ aw,
                                                const float* __restrict__ ab,
                                                float* __restrict__ m,
                                                int* __restrict__ cnt)
{
    int b = blockIdx.x;
    int tid = threadIdx.x;
    if (b == 0 && tid < 128) cnt[tid] = 0;   // band counters for proj+LN fusion
    if (b >= 432) {
        __shared__ float s[CC];
        __shared__ float red[4][64];
        for (int i = tid; i < CC; i += 256) {
            float c = cond[i];
            s[i] = c / (1.f + __expf(-c));
        }
        __syncthreads();
        int c  = tid & 63;
        int ks = tid >> 6;
        int col = (b - 432) * 64 + c;
        float acc = 0.f;
        for (int k = ks * 96; k < (ks + 1) * 96; ++k)
            acc += s[k] * aw[(size_t)k * (6*CC) + col];
        red[ks][c] = acc;
        __syncthreads();
        if (tid < 64)
            m[col] = red[0][c] + red[1][c] + red[2][c] + red[3][c] + ab[col];
        return;
    }
    __shared__ float t[64][65];
    const float* in; bf16* outp; int K, N, lid;
    if (b < 108)       { in = qkv_w;  outp = qkv_wt;  K = 384;  N = 1152; lid = b; }
    else if (b < 144)  { in = proj_w; outp = proj_wt; K = 384;  N = 384;  lid = b - 108; }
    else if (b < 288)  { in = fc1_w;  outp = fc1_wt;  K = 384;  N = 1536; lid = b - 144; }
    else               { in = fc2_w;  outp = fc2_wt;  K = 1536; N = 384;  lid = b - 288; }
    int nbn = N >> 6;
    int bn = (lid % nbn) << 6, bk = (lid / nbn) << 6;
    int c4 = (tid & 15) * 4, r0 = tid >> 4;
    #pragma unroll
    for (int p = 0; p < 4; ++p) {
        int r = r0 + p * 16;
        float4 v = *(const float4*)&in[(size_t)(bk + r) * N + bn + c4];
        t[r][c4+0] = v.x; t[r][c4+1] = v.y; t[r][c4+2] = v.z; t[r][c4+3] = v.w;
    }
    __syncthreads();
    #pragma unroll
    for (int p = 0; p < 4; ++p) {
        int n = r0 + p * 16;
        ushort4 w;
        w.x = __bfloat16_as_ushort(f2bf(t[c4+0][n]));
        w.y = __bfloat16_as_ushort(f2bf(t[c4+1][n]));
        w.z = __bfloat16_as_ushort(f2bf(t[c4+2][n]));
        w.w = __bfloat16_as_ushort(f2bf(t[c4+3][n]));
        *(ushort4*)&outp[(size_t)(bn + n) * K + bk + c4] = w;
    }
}

// ---------------------------------------------------------------------------
// Kernel 2: y = LN(x) * (1 + sc) + sh   -> bf16   (LN1)
// ---------------------------------------------------------------------------
__global__ __launch_bounds__(128) void ln_mod_k(const float* __restrict__ xin,
                                                const float* __restrict__ sh,
                                                const float* __restrict__ sc,
                                                bf16* __restrict__ yout)
{
    int t = blockIdx.x;
    int tid = threadIdx.x;
    const float* xr = xin + (size_t)t * CC;
    float v0 = xr[tid], v1 = xr[tid + 128], v2 = xr[tid + 256];
    float s  = v0 + v1 + v2;
    float ss = v0*v0 + v1*v1 + v2*v2;
    #pragma unroll
    for (int off = 32; off; off >>= 1) {
        s  += __shfl_down(s,  off);
        ss += __shfl_down(ss, off);
    }
    __shared__ float red[4];
    int wid = tid >> 6;
    if ((tid & 63) == 0) { red[wid*2] = s; red[wid*2+1] = ss; }
    __syncthreads();
    s  = red[0] + red[2];
    ss = red[1] + red[3];
    float mean = s * (1.f / CC);
    float var  = ss * (1.f / CC) - mean * mean;
    float rstd = rsqrtf(var + LN_EPS);
    bf16* yr = yout + (size_t)t * CC;
    yr[tid      ] = f2bf((v0 - mean) * rstd * (1.f + sc[tid      ]) + sh[tid      ]);
    yr[tid + 128] = f2bf((v1 - mean) * rstd * (1.f + sc[tid + 128]) + sh[tid + 128]);
    yr[tid + 256] = f2bf((v2 - mean) * rstd * (1.f + sc[tid + 256]) + sh[tid + 256]);
}

// ---------------------------------------------------------------------------
// Kernel 3: MFMA bf16 GEMM (R12-proven: gload_lds + XOR swizzle + counted-
// vmcnt pipe + LDS-staged epilogue).  NEW: LNF=1 (only with EPI=1, BM=32,
// TPB=256, N=CC) fuses LN2+modulation: the last block of each 32-row band
// re-reads its band of x1 and writes y = LN(x1)*(1+sc_m)+sh_m.
// ---------------------------------------------------------------------------
#define GBK 64

template<int EPI, int LNF, typename OutT, int BM, int BN, int TPB, int DEPTH>
__global__ __launch_bounds__(TPB) void mgemm_k(const bf16* __restrict__ A,
                                               const bf16* __restrict__ Bt,
                                               const float* __restrict__ bias,
                                               const float* __restrict__ resid,
                                               const float* __restrict__ gvec,
                                               const float* __restrict__ modv,
                                               bf16* __restrict__ yout,
                                               int* __restrict__ cnt,
                                               OutT* __restrict__ out,
                                               int M, int N, int Kd)
{
    constexpr int WR = 2, WC = TPB / 128;
    constexpr int FM = BM / WR / 16, FN = BN / WC / 16;
    constexpr int RPP = TPB / 8;
    constexpr int PA = BM / RPP > 0 ? BM / RPP : 1;
    constexpr int PB = BN / RPP > 0 ? BN / RPP : 1;
    constexpr int LDST = PA + PB;
    constexpr int STAGE_BYTES = DEPTH * (BM + BN) * GBK * 2;
    constexpr int EPI_BYTES = (EPI == 1) ? BM * (BN + 4) * 4 : BM * (BN + 8) * 2;
    constexpr int SMEM = STAGE_BYTES > EPI_BYTES ? STAGE_BYTES : EPI_BYTES;
    __shared__ __align__(16) char smem[SMEM];
    bf16* As = (bf16*)smem;
    bf16* Bs = (bf16*)(smem + DEPTH * BM * GBK * 2);

    int tid = threadIdx.x;
    int wid = tid >> 6, lane = tid & 63;
    int wm = wid / WC, wn = wid % WC;

    int gx = gridDim.x;
    int nwg = gx * gridDim.y;
    int bid = blockIdx.y * gx + blockIdx.x;
    int swz = (bid & 7) * (nwg >> 3) + (bid >> 3);
    int bx = swz % gx, by = swz / gx;

    int row_base = by * BM;
    int col_base = bx * BN;

    int l8 = lane >> 3;
    int cs = ((lane & 7) ^ l8) * 8;
    int xr = (lane & 7) << 4;
    int bcol = (lane >> 4) * 16;

    f32x4 acc[FM][FN] = {};
    const int nt = Kd / GBK;

    auto STAGE = [&](int buf, int t) {
        int k0 = t * GBK;
        #pragma unroll
        for (int p = 0; p < PA; ++p) {
            int rb = (p * RPP + wid * 8) % BM;
            __builtin_amdgcn_global_load_lds(
                (gptr_t)(const void*)(A + (size_t)(row_base + rb + l8) * Kd + k0 + cs),
                (lptr_t)(void*)(As + (buf * BM + rb) * GBK), 16, 0, 0);
        }
        #pragma unroll
        for (int p = 0; p < PB; ++p) {
            int rb = (p * RPP + wid * 8) % BN;
            __builtin_amdgcn_global_load_lds(
                (gptr_t)(const void*)(Bt + (size_t)(col_base + rb + l8) * Kd + k0 + cs),
                (lptr_t)(void*)(Bs + (buf * BN + rb) * GBK), 16, 0, 0);
        }
    };

    #pragma unroll
    for (int d = 0; d < DEPTH - 1; ++d) STAGE(d, d);

    int cur = 0;
    for (int t = 0; t < nt; ++t) {
        if (t + DEPTH - 1 < nt)
            STAGE((cur + DEPTH - 1) % DEPTH, t + DEPTH - 1);
        int ahead = min(nt - 1, t + DEPTH - 1) - t;
        if constexpr (DEPTH == 3) {
            if (ahead == 2)      asm volatile("s_waitcnt vmcnt(%0)" :: "n"(2*LDST) : "memory");
            else if (ahead == 1) asm volatile("s_waitcnt vmcnt(%0)" :: "n"(LDST)   : "memory");
            else                 asm volatile("s_waitcnt vmcnt(0)" ::: "memory");
        } else {
            if (ahead == 1)      asm volatile("s_waitcnt vmcnt(%0)" :: "n"(LDST)   : "memory");
            else                 asm volatile("s_waitcnt vmcnt(0)" ::: "memory");
        }
        __builtin_amdgcn_sched_barrier(0);
        __builtin_amdgcn_s_barrier();
        __builtin_amdgcn_sched_barrier(0);
        #pragma unroll
        for (int kk = 0; kk < GBK; kk += 32) {
            bf16x8 af[FM], bfr[FN];
            #pragma unroll
            for (int m2 = 0; m2 < FM; ++m2) {
                int R = wm*(BM/WR) + m2*16 + (lane & 15);
                af[m2] = *(const bf16x8*)((const char*)As + (cur*BM + R)*128 + ((kk*2 + bcol) ^ xr));
            }
            #pragma unroll
            for (int n = 0; n < FN; ++n) {
                int R = wn*(BN/WC) + n*16 + (lane & 15);
                bfr[n] = *(const bf16x8*)((const char*)Bs + (cur*BN + R)*128 + ((kk*2 + bcol) ^ xr));
            }
            #pragma unroll
            for (int m2 = 0; m2 < FM; ++m2)
                #pragma unroll
                for (int n = 0; n < FN; ++n)
                    acc[m2][n] = __builtin_amdgcn_mfma_f32_16x16x32_bf16(af[m2], bfr[n], acc[m2][n], 0, 0, 0);
        }
        __builtin_amdgcn_sched_barrier(0);
        __builtin_amdgcn_s_barrier();
        __builtin_amdgcn_sched_barrier(0);
        cur = (cur + 1 == DEPTH) ? 0 : cur + 1;
    }

    // ---- LDS-staged vectorized epilogue ----
    int cl = lane & 15, rq = lane >> 4;
    if constexpr (EPI == 1) {
        float* et = (float*)smem;
        #pragma unroll
        for (int m2 = 0; m2 < FM; ++m2)
            #pragma unroll
            for (int n = 0; n < FN; ++n) {
                int col = wn*(BN/WC) + n*16 + cl;
                float bv = bias[col_base + col];
                #pragma unroll
                for (int j = 0; j < 4; ++j) {
                    int row = wm*(BM/WR) + m2*16 + rq*4 + j;
                    et[row*(BN+4) + col] = acc[m2][n][j] + bv;
                }
            }
        __syncthreads();
        constexpr int CH = BN / 4;
        #pragma unroll
        for (int p = 0; p < (BM*CH)/TPB; ++p) {
            int idx = p * TPB + tid;
            int row = idx / CH, ch = idx % CH;
            float4 v = *(const float4*)&et[row*(BN+4) + ch*4];
            size_t gidx = (size_t)(row_base + row) * N + col_base + ch*4;
            float4 r = *(const float4*)&resid[gidx];
            float4 g = *(const float4*)&gvec[col_base + ch*4];
            float4 o;
            o.x = r.x + g.x * v.x;
            o.y = r.y + g.y * v.y;
            o.z = r.z + g.z * v.z;
            o.w = r.w + g.w * v.w;
            *(float4*)&((float*)out)[gidx] = o;
        }
        if constexpr (LNF) {
            // last block of this 32-row band computes y = LN(x1)*(1+sc)+sh
            __threadfence();
            __shared__ int lastf;
            if (tid == 0) {
                int old = atomicAdd(&cnt[by], 1);
                lastf = (old == (int)gridDim.x - 1);
                if (lastf) atomicExch(&cnt[by], 0);   // reset for next call
            }
            __syncthreads();
            if (!lastf) return;
            __threadfence();
            int r  = tid >> 3;        // 32 rows, 8 threads/row
            int sg = tid & 7;         // segment of 48 cols
            const float* x1 = (const float*)out + (size_t)(row_base + r) * CC + sg * 48;
            float s = 0.f, ss = 0.f;
            #pragma unroll
            for (int c = 0; c < 48; c += 4) {
                float4 v = *(const float4*)&x1[c];
                s  += v.x + v.y + v.z + v.w;
                ss += v.x*v.x + v.y*v.y + v.z*v.z + v.w*v.w;
            }
            #pragma unroll
            for (int off = 1; off < 8; off <<= 1) {
                s  += __shfl_xor(s,  off);
                ss += __shfl_xor(ss, off);
            }
            float mean = s * (1.f / CC);
            float rstd = rsqrtf(ss * (1.f / CC) - mean * mean + LN_EPS);
            bf16* yr = yout + (size_t)(row_base + r) * CC + sg * 48;
            #pragma unroll
            for (int c = 0; c < 48; c += 8) {
                float4 va = *(const float4*)&x1[c];
                float4 vb = *(const float4*)&x1[c + 4];
                float4 ha = *(const float4*)&modv[sg*48 + c];
                float4 hb = *(const float4*)&modv[sg*48 + c + 4];
                float4 ca = *(const float4*)&modv[CC + sg*48 + c];
                float4 cb = *(const float4*)&modv[CC + sg*48 + c + 4];
                bf16x8 w;
                w[0] = (short)__bfloat16_as_ushort(f2bf((va.x-mean)*rstd*(1.f+ca.x)+ha.x));
                w[1] = (short)__bfloat16_as_ushort(f2bf((va.y-mean)*rstd*(1.f+ca.y)+ha.y));
                w[2] = (short)__bfloat16_as_ushort(f2bf((va.z-mean)*rstd*(1.f+ca.z)+ha.z));
                w[3] = (short)__bfloat16_as_ushort(f2bf((va.w-mean)*rstd*(1.f+ca.w)+ha.w));
                w[4] = (short)__bfloat16_as_ushort(f2bf((vb.x-mean)*rstd*(1.f+cb.x)+hb.x));
                w[5] = (short)__bfloat16_as_ushort(f2bf((vb.y-mean)*rstd*(1.f+cb.y)+hb.y));
                w[6] = (short)__bfloat16_as_ushort(f2bf((vb.z-mean)*rstd*(1.f+cb.z)+hb.z));
                w[7] = (short)__bfloat16_as_ushort(f2bf((vb.w-mean)*rstd*(1.f+cb.w)+hb.w));
                *(bf16x8*)&yr[c] = w;
            }
        }
    } else {
        bf16* et = (bf16*)smem;
        #pragma unroll
        for (int m2 = 0; m2 < FM; ++m2)
            #pragma unroll
            for (int n = 0; n < FN; ++n) {
                int col = wn*(BN/WC) + n*16 + cl;
                float bv = bias[col_base + col];
                #pragma unroll
                for (int j = 0; j < 4; ++j) {
                    int row = wm*(BM/WR) + m2*16 + rq*4 + j;
                    float v = acc[m2][n][j] + bv;
                    if constexpr (EPI == 2) {        // gelu = v*sigmoid(2u)
                        float u = 0.7978845608028654f * (v + 0.044715f * v * v * v);
                        v = v / (1.f + __expf(-2.f * u));
                    }
                    et[row*(BN+8) + col] = f2bf(v);
                }
            }
        __syncthreads();
        constexpr int CH = BN / 8;
        #pragma unroll
        for (int p = 0; p < (BM*CH)/TPB; ++p) {
            int idx = p * TPB + tid;
            int row = idx / CH, ch = idx % CH;
            bf16x8 v = *(const bf16x8*)&et[row*(BN+8) + ch*8];
            *(bf16x8*)&((bf16*)out)[(size_t)(row_base + row) * N + col_base + ch*8] = v;
        }
    }
}

// ---------------------------------------------------------------------------
// Kernel 4: NATTEN 7x7 — MFMA-tiled (proven R10, unchanged)
// ---------------------------------------------------------------------------
#define QOFF 0
#define KOFF 8192
#define VOFF 36864
#define POFF 65536

__global__ __launch_bounds__(256) void natten_k(const bf16* __restrict__ qkv,
                                                bf16* __restrict__ o)
{
    __shared__ __align__(16) char lds[95232];
    int tid = threadIdx.x;
    int wid = tid >> 6, lane = tid & 63;
    int b = blockIdx.x;
    int h = b % NHD, tile = b / NHD;
    int R0 = (tile >> 3) << 3, C0 = (tile & 7) << 3;
    int wr0 = min(max(R0 - 3, 0), GH - 14);
    int wc0 = min(max(C0 - 3, 0), GW - 14);

    int l8 = lane >> 3, c8 = lane & 7;
    int cs = ((c8 ^ l8) << 3);

    #pragma unroll
    for (int p = 0; p < 2; ++p) {
        int rb = p * 32 + wid * 8;
        int q  = rb + l8;
        int token = (R0 + (q >> 3)) * GW + C0 + (q & 7);
        __builtin_amdgcn_global_load_lds(
            (gptr_t)(const void*)(qkv + (size_t)token * (3*CC) + h * DH + cs),
            (lptr_t)(void*)(lds + QOFF + rb * 128), 16, 0, 0);
    }
    #pragma unroll
    for (int p = 0; p < 7; ++p) {
        int rb = p * 32 + wid * 8;
        int key = rb + l8;
        if (key < 196) {
            int kr = (key * 586) >> 13;
            int kc = key - 14 * kr;
            int token = (wr0 + kr) * GW + wc0 + kc;
            const bf16* base = qkv + (size_t)token * (3*CC) + h * DH + cs;
            __builtin_amdgcn_global_load_lds(
                (gptr_t)(const void*)(base + CC),
                (lptr_t)(void*)(lds + KOFF + rb * 128), 16, 0, 0);
            __builtin_amdgcn_global_load_lds(
                (gptr_t)(const void*)(base + 2*CC),
                (lptr_t)(void*)(lds + VOFF + rb * 128), 16, 0, 0);
        }
    }
    for (int i = tid; i < 896; i += 256)
        *(unsigned int*)(lds + VOFF + 196*128 + i * 4) = 0u;
    for (int i = tid; i < 64*18; i += 256) {
        int row = i / 18, seg = i % 18;
        *(unsigned int*)(lds + POFF + row * 464 + 392 + seg * 4) = 0u;
    }
    __syncthreads();

    int qme = wid * 16 + (lane & 15);
    int qr = R0 + (qme >> 3), qc = C0 + (qme & 7);
    int sh = min(max(qr - 3, 0), GH - KW);
    int sw = min(max(qc - 3, 0), GW - KW);

    bf16x8 bq[2];
    #pragma unroll
    for (int kk = 0; kk < 2; ++kk)
        bq[kk] = *(const bf16x8*)(lds + QOFF + qme * 128 +
                  ((kk * 64 + (lane >> 4) * 16) ^ ((qme & 7) << 4)));

    f32x4 sc[13] = {};
    #pragma unroll
    for (int m = 0; m < 13; ++m) {
        #pragma unroll
        for (int kk = 0; kk < 2; ++kk) {
            int R = m * 16 + (lane & 15);
            bf16x8 af = *(const bf16x8*)(lds + KOFF + R * 128 +
                         ((kk * 64 + (lane >> 4) * 16) ^ ((R & 7) << 4)));
            sc[m] = __builtin_amdgcn_mfma_f32_16x16x32_bf16(af, bq[kk], sc[m], 0, 0, 0);
        }
    }
    float mx = -3e38f;
    #pragma unroll
    for (int m = 0; m < 13; ++m) {
        #pragma unroll
        for (int j = 0; j < 4; ++j) {
            int key = m * 16 + (lane >> 4) * 4 + j;
            int kr = (key * 586) >> 13;
            int kc = key - 14 * kr;
            int kg = wr0 + kr, cg = wc0 + kc;
            bool val = (kg >= sh) && (kg <= sh + 6) && (cg >= sw) && (cg <= sw + 6);
            float s = val ? sc[m][j] * 0.125f : -3e38f;
            sc[m][j] = s;
            mx = fmaxf(mx, s);
        }
    }
    mx = fmaxf(mx, __shfl_xor(mx, 16));
    mx = fmaxf(mx, __shfl_xor(mx, 32));
    float sum = 0.f;
    #pragma unroll
    for (int m = 0; m < 13; ++m)
        #pragma unroll
        for (int j = 0; j < 4; ++j) {
            float e = __expf(sc[m][j] - mx);
            sc[m][j] = e;
            sum += e;
        }
    sum += __shfl_xor(sum, 16);
    sum += __shfl_xor(sum, 32);
    float inv = 1.f / sum;

    #pragma unroll
    for (int m = 0; m < 13; ++m)
        #pragma unroll
        for (int j = 0; j < 4; ++j) {
            int key = m * 16 + (lane >> 4) * 4 + j;
            *(bf16*)(lds + POFF + qme * 464 + key * 2) = f2bf(sc[m][j]);
        }
    asm volatile("s_waitcnt lgkmcnt(0)" ::: "memory");
    __builtin_amdgcn_sched_barrier(0);

    f32x4 oacc[4] = {};
    #pragma unroll
    for (int kk = 0; kk < 7; ++kk) {
        bf16x8 af = *(const bf16x8*)(lds + POFF + qme * 464 + kk * 64 + (lane >> 4) * 16);
        #pragma unroll
        for (int n = 0; n < 4; ++n) {
            int dd = n * 16 + (lane & 15);
            int gch = dd >> 3, dby = (dd & 7) * 2;
            bf16x8 bv;
            #pragma unroll
            for (int j = 0; j < 8; ++j) {
                int key = kk * 32 + (lane >> 4) * 8 + j;
                ((short*)&bv)[j] = *(const short*)(lds + VOFF + key * 128 +
                                    ((gch ^ (key & 7)) << 4) + dby);
            }
            oacc[n] = __builtin_amdgcn_mfma_f32_16x16x32_bf16(af, bv, oacc[n], 0, 0, 0);
        }
    }

    #pragma unroll
    for (int j = 0; j < 4; ++j) {
        int idxq = ((lane >> 4) << 2) + j;
        float iv = __shfl(inv, (lane & 48) | idxq);
        int q2 = wid * 16 + idxq;
        int token = (R0 + (q2 >> 3)) * GW + C0 + (q2 & 7);
        #pragma unroll
        for (int n = 0; n < 4; ++n) {
            int d = n * 16 + (lane & 15);
            o[(size_t)token * CC + h * DH + d] = f2bf(oacc[n][j] * iv);
        }
    }
}

// ---------------------------------------------------------------------------
// launch  (7 dispatches)
// ---------------------------------------------------------------------------
extern "C" void kernel_launch(void* const* d_in, const int* in_sizes, int n_in,
                              void* d_out, int out_size, void* d_ws, size_t ws_size,
                              hipStream_t stream)
{
    const float* x      = (const float*)d_in[0];
    const float* cond   = (const float*)d_in[1];
    const float* qkv_w  = (const float*)d_in[2];
    const float* qkv_b  = (const float*)d_in[3];
    const float* proj_w = (const float*)d_in[4];
    const float* proj_b = (const float*)d_in[5];
    const float* fc1_w  = (const float*)d_in[6];
    const float* fc1_b  = (const float*)d_in[7];
    const float* fc2_w  = (const float*)d_in[8];
    const float* fc2_b  = (const float*)d_in[9];
    const float* ada_w  = (const float*)d_in[10];
    const float* ada_b  = (const float*)d_in[11];
    float* out = (float*)d_out;

    char* p = (char*)d_ws;
    float* m       = (float*)p;            p += 6*CC*sizeof(float);
    bf16* y        = (bf16*)p;             p += (size_t)NTOK*CC*2;
    bf16* qkv      = (bf16*)p;             p += (size_t)NTOK*(3*CC)*2;
    bf16* attn_o   = (bf16*)p;             p += (size_t)NTOK*CC*2;
    bf16* hdn      = (bf16*)p;             p += (size_t)NTOK*(4*CC)*2;
    bf16* qkv_wt   = (bf16*)p;             p += (size_t)(3*CC)*CC*2;
    bf16* proj_wt  = (bf16*)p;             p += (size_t)CC*CC*2;
    bf16* fc1_wt   = (bf16*)p;             p += (size_t)(4*CC)*CC*2;
    bf16* fc2_wt   = (bf16*)p;             p += (size_t)CC*(4*CC)*2;
    int*  cnt      = (int*)p;              p += 128*sizeof(int);

    const float* sh_a = m;
    const float* sc_a = m + CC;
    const float* g_a  = m + 2*CC;
    const float* g_m  = m + 5*CC;

    // 1. transposes + ada + counter zero
    wt_ada_k<<<468, 256, 0, stream>>>(qkv_w, proj_w, fc1_w, fc2_w,
                                      qkv_wt, proj_wt, fc1_wt, fc2_wt,
                                      cond, ada_w, ada_b, m, cnt);
    // 2. y = LN(x)*(1+sc_a)+sh_a
    ln_mod_k<<<NTOK, 128, 0, stream>>>(x, sh_a, sc_a, y);
    // 3. qkv = y @ qkv_w + qkv_b
    mgemm_k<0, 0, bf16, 64, 128, 256, 2><<<dim3((3*CC)/128, NTOK/64), 256, 0, stream>>>(
        y, qkv_wt, qkv_b, nullptr, nullptr, nullptr, nullptr, nullptr,
        qkv, NTOK, 3*CC, CC);
    // 4. neighborhood attention
    natten_k<<<(NTOK/64)*NHD, 256, 0, stream>>>(qkv, attn_o);
    // 5. x1 = x + g_a*(attn_o @ proj_w + proj_b); last band block also writes
    //    y = LN(x1)*(1+sc_m)+sh_m   (LNF=1, modv = m+3CC)
    mgemm_k<1, 1, float, 32, 64, 256, 3><<<dim3(CC/64, NTOK/32), 256, 0, stream>>>(
        attn_o, proj_wt, proj_b, x, g_a, m + 3*CC, y, cnt,
        out, NTOK, CC, CC);
    // 6. hdn = gelu(y @ fc1_w + fc1_b)
    mgemm_k<2, 0, bf16, 64, 128, 256, 2><<<dim3((4*CC)/128, NTOK/64), 256, 0, stream>>>(
        y, fc1_wt, fc1_b, nullptr, nullptr, nullptr, nullptr, nullptr,
        hdn, NTOK, 4*CC, CC);
    // 7. out = x1 + g_m * (hdn @ fc2_w + fc2_b)
    mgemm_k<1, 0, float, 32, 64, 256, 3><<<dim3(CC/64, NTOK/32), 256, 0, stream>>>(
        hdn, fc2_wt, fc2_b, out, g_m, nullptr, nullptr, nullptr,
        out, NTOK, CC, 4*CC);
}

// Round 15
// 80.374 us; speedup vs baseline: 2.1644x; 2.1644x over previous
//
#include <hip/hip_runtime.h>
#include <hip/hip_bf16.h>
#include <math.h>

// Problem constants
#define GH 64
#define GW 64
#define CC 384
#define NHD 6
#define KW 7
#define DH 64
#define NTOK (GH*GW)          // 4096
#define LN_EPS 1e-6f

typedef __attribute__((ext_vector_type(4))) float f32x4;
typedef __attribute__((ext_vector_type(8))) short bf16x8;
typedef __hip_bfloat16 bf16;

typedef const __attribute__((address_space(1))) unsigned int* gptr_t;
typedef __attribute__((address_space(3))) unsigned int* lptr_t;

__device__ __forceinline__ float bf2f(unsigned int u16) {
    union { unsigned int i; float f; } c; c.i = u16 << 16; return c.f;
}
__device__ __forceinline__ bf16 f2bf(float f) { return __float2bfloat16(f); }

// ---------------------------------------------------------------------------
// Kernel 1: fused {4 weight transposes (64x64 tiles, vectorized)} + {ada}.
// ---------------------------------------------------------------------------
__global__ __launch_bounds__(256) void wt_ada_k(const float* __restrict__ qkv_w,
                                                const float* __restrict__ proj_w,
                                                const float* __restrict__ fc1_w,
                                                const float* __restrict__ fc2_w,
                                                bf16* __restrict__ qkv_wt,
                                                bf16* __restrict__ proj_wt,
                                                bf16* __restrict__ fc1_wt,
                                                bf16* __restrict__ fc2_wt,
                                                const float* __restrict__ cond,
                                                const float* __restrict__ aw,
                                                const float* __restrict__ ab,
                                                float* __restrict__ m)
{
    int b = blockIdx.x;
    int tid = threadIdx.x;
    if (b >= 432) {
        __shared__ float s[CC];
        __shared__ float red[4][64];
        for (int i = tid; i < CC; i += 256) {
            float c = cond[i];
            s[i] = c / (1.f + __expf(-c));
        }
        __syncthreads();
        int c  = tid & 63;
        int ks = tid >> 6;
        int col = (b - 432) * 64 + c;
        float acc = 0.f;
        for (int k = ks * 96; k < (ks + 1) * 96; ++k)
            acc += s[k] * aw[(size_t)k * (6*CC) + col];
        red[ks][c] = acc;
        __syncthreads();
        if (tid < 64)
            m[col] = red[0][c] + red[1][c] + red[2][c] + red[3][c] + ab[col];
        return;
    }
    __shared__ float t[64][65];
    const float* in; bf16* outp; int K, N, lid;
    if (b < 108)       { in = qkv_w;  outp = qkv_wt;  K = 384;  N = 1152; lid = b; }
    else if (b < 144)  { in = proj_w; outp = proj_wt; K = 384;  N = 384;  lid = b - 108; }
    else if (b < 288)  { in = fc1_w;  outp = fc1_wt;  K = 384;  N = 1536; lid = b - 144; }
    else               { in = fc2_w;  outp = fc2_wt;  K = 1536; N = 384;  lid = b - 288; }
    int nbn = N >> 6;
    int bn = (lid % nbn) << 6, bk = (lid / nbn) << 6;
    int c4 = (tid & 15) * 4, r0 = tid >> 4;
    #pragma unroll
    for (int p = 0; p < 4; ++p) {
        int r = r0 + p * 16;
        float4 v = *(const float4*)&in[(size_t)(bk + r) * N + bn + c4];
        t[r][c4+0] = v.x; t[r][c4+1] = v.y; t[r][c4+2] = v.z; t[r][c4+3] = v.w;
    }
    __syncthreads();
    #pragma unroll
    for (int p = 0; p < 4; ++p) {
        int n = r0 + p * 16;
        ushort4 w;
        w.x = __bfloat16_as_ushort(f2bf(t[c4+0][n]));
        w.y = __bfloat16_as_ushort(f2bf(t[c4+1][n]));
        w.z = __bfloat16_as_ushort(f2bf(t[c4+2][n]));
        w.w = __bfloat16_as_ushort(f2bf(t[c4+3][n]));
        *(ushort4*)&outp[(size_t)(bn + n) * K + bk + c4] = w;
    }
}

// ---------------------------------------------------------------------------
// Kernel 2: y = LN(x)*(1+sc)+sh -> bf16.  256 threads, 2 tokens per block.
// ---------------------------------------------------------------------------
__global__ __launch_bounds__(256) void ln_mod_k(const float* __restrict__ xin,
                                                const float* __restrict__ sh,
                                                const float* __restrict__ sc,
                                                bf16* __restrict__ yout)
{
    int tok = blockIdx.x * 2 + (threadIdx.x >> 7);
    int lt  = threadIdx.x & 127;
    const float* xr = xin + (size_t)tok * CC;
    float v0 = xr[lt], v1 = xr[lt + 128], v2 = xr[lt + 256];
    float s  = v0 + v1 + v2;
    float ss = v0*v0 + v1*v1 + v2*v2;
    #pragma unroll
    for (int off = 32; off; off >>= 1) {
        s  += __shfl_down(s,  off);
        ss += __shfl_down(ss, off);
    }
    __shared__ float red[8];
    int wid = threadIdx.x >> 6;
    if ((threadIdx.x & 63) == 0) { red[wid*2] = s; red[wid*2+1] = ss; }
    __syncthreads();
    int base = (threadIdx.x >> 7) * 4;
    s  = red[base+0] + red[base+2];
    ss = red[base+1] + red[base+3];
    float mean = s * (1.f / CC);
    float var  = ss * (1.f / CC) - mean * mean;
    float rstd = rsqrtf(var + LN_EPS);
    bf16* yr = yout + (size_t)tok * CC;
    yr[lt      ] = f2bf((v0 - mean) * rstd * (1.f + sc[lt      ]) + sh[lt      ]);
    yr[lt + 128] = f2bf((v1 - mean) * rstd * (1.f + sc[lt + 128]) + sh[lt + 128]);
    yr[lt + 256] = f2bf((v2 - mean) * rstd * (1.f + sc[lt + 256]) + sh[lt + 256]);
}

// ---------------------------------------------------------------------------
// Kernel 3: MFMA bf16 GEMM, gload_lds(16B) + XOR swizzle + counted-vmcnt
// DEPTH pipeline + LDS-staged vectorized epilogue (proven R5-R12).
// ---------------------------------------------------------------------------
#define GBK 64

template<int EPI, typename OutT, int BM, int BN, int TPB, int DEPTH>
__global__ __launch_bounds__(TPB) void mgemm_k(const bf16* __restrict__ A,
                                               const bf16* __restrict__ Bt,
                                               const float* __restrict__ bias,
                                               const float* __restrict__ resid,
                                               const float* __restrict__ gvec,
                                               OutT* __restrict__ out,
                                               int M, int N, int Kd)
{
    constexpr int WR = 2, WC = TPB / 128;
    constexpr int FM = BM / WR / 16, FN = BN / WC / 16;
    constexpr int RPP = TPB / 8;
    constexpr int PA = BM / RPP > 0 ? BM / RPP : 1;
    constexpr int PB = BN / RPP > 0 ? BN / RPP : 1;
    constexpr int LDST = PA + PB;
    constexpr int STAGE_BYTES = DEPTH * (BM + BN) * GBK * 2;
    constexpr int EPI_BYTES = (EPI == 1) ? BM * (BN + 4) * 4 : BM * (BN + 8) * 2;
    constexpr int SMEM = STAGE_BYTES > EPI_BYTES ? STAGE_BYTES : EPI_BYTES;
    __shared__ __align__(16) char smem[SMEM];
    bf16* As = (bf16*)smem;
    bf16* Bs = (bf16*)(smem + DEPTH * BM * GBK * 2);

    int tid = threadIdx.x;
    int wid = tid >> 6, lane = tid & 63;
    int wm = wid / WC, wn = wid % WC;

    int gx = gridDim.x;
    int nwg = gx * gridDim.y;
    int bid = blockIdx.y * gx + blockIdx.x;
    int swz = (bid & 7) * (nwg >> 3) + (bid >> 3);
    int bx = swz % gx, by = swz / gx;

    int row_base = by * BM;
    int col_base = bx * BN;

    int l8 = lane >> 3;
    int cs = ((lane & 7) ^ l8) * 8;
    int xr = (lane & 7) << 4;
    int bcol = (lane >> 4) * 16;

    f32x4 acc[FM][FN] = {};
    const int nt = Kd / GBK;

    auto STAGE = [&](int buf, int t) {
        int k0 = t * GBK;
        #pragma unroll
        for (int p = 0; p < PA; ++p) {
            int rb = (p * RPP + wid * 8) % BM;
            __builtin_amdgcn_global_load_lds(
                (gptr_t)(const void*)(A + (size_t)(row_base + rb + l8) * Kd + k0 + cs),
                (lptr_t)(void*)(As + (buf * BM + rb) * GBK), 16, 0, 0);
        }
        #pragma unroll
        for (int p = 0; p < PB; ++p) {
            int rb = (p * RPP + wid * 8) % BN;
            __builtin_amdgcn_global_load_lds(
                (gptr_t)(const void*)(Bt + (size_t)(col_base + rb + l8) * Kd + k0 + cs),
                (lptr_t)(void*)(Bs + (buf * BN + rb) * GBK), 16, 0, 0);
        }
    };

    #pragma unroll
    for (int d = 0; d < DEPTH - 1; ++d) STAGE(d, d);

    int cur = 0;
    for (int t = 0; t < nt; ++t) {
        if (t + DEPTH - 1 < nt)
            STAGE((cur + DEPTH - 1) % DEPTH, t + DEPTH - 1);
        int ahead = min(nt - 1, t + DEPTH - 1) - t;
        if constexpr (DEPTH == 3) {
            if (ahead == 2)      asm volatile("s_waitcnt vmcnt(%0)" :: "n"(2*LDST) : "memory");
            else if (ahead == 1) asm volatile("s_waitcnt vmcnt(%0)" :: "n"(LDST)   : "memory");
            else                 asm volatile("s_waitcnt vmcnt(0)" ::: "memory");
        } else {
            if (ahead == 1)      asm volatile("s_waitcnt vmcnt(%0)" :: "n"(LDST)   : "memory");
            else                 asm volatile("s_waitcnt vmcnt(0)" ::: "memory");
        }
        __builtin_amdgcn_sched_barrier(0);
        __builtin_amdgcn_s_barrier();
        __builtin_amdgcn_sched_barrier(0);
        #pragma unroll
        for (int kk = 0; kk < GBK; kk += 32) {
            bf16x8 af[FM], bfr[FN];
            #pragma unroll
            for (int m = 0; m < FM; ++m) {
                int R = wm*(BM/WR) + m*16 + (lane & 15);
                af[m]  = *(const bf16x8*)((const char*)As + (cur*BM + R)*128 + ((kk*2 + bcol) ^ xr));
            }
            #pragma unroll
            for (int n = 0; n < FN; ++n) {
                int R = wn*(BN/WC) + n*16 + (lane & 15);
                bfr[n] = *(const bf16x8*)((const char*)Bs + (cur*BN + R)*128 + ((kk*2 + bcol) ^ xr));
            }
            #pragma unroll
            for (int m = 0; m < FM; ++m)
                #pragma unroll
                for (int n = 0; n < FN; ++n)
                    acc[m][n] = __builtin_amdgcn_mfma_f32_16x16x32_bf16(af[m], bfr[n], acc[m][n], 0, 0, 0);
        }
        __builtin_amdgcn_sched_barrier(0);
        __builtin_amdgcn_s_barrier();
        __builtin_amdgcn_sched_barrier(0);
        cur = (cur + 1 == DEPTH) ? 0 : cur + 1;
    }

    // ---- LDS-staged vectorized epilogue ----
    int cl = lane & 15, rq = lane >> 4;
    if constexpr (EPI == 1) {
        float* et = (float*)smem;
        #pragma unroll
        for (int m = 0; m < FM; ++m)
            #pragma unroll
            for (int n = 0; n < FN; ++n) {
                int col = wn*(BN/WC) + n*16 + cl;
                float bv = bias[col_base + col];
                #pragma unroll
                for (int j = 0; j < 4; ++j) {
                    int row = wm*(BM/WR) + m*16 + rq*4 + j;
                    et[row*(BN+4) + col] = acc[m][n][j] + bv;
                }
            }
        __syncthreads();
        constexpr int CH = BN / 4;
        #pragma unroll
        for (int p = 0; p < (BM*CH)/TPB; ++p) {
            int idx = p * TPB + tid;
            int row = idx / CH, ch = idx % CH;
            float4 v = *(const float4*)&et[row*(BN+4) + ch*4];
            size_t gidx = (size_t)(row_base + row) * N + col_base + ch*4;
            float4 r = *(const float4*)&resid[gidx];
            float4 g = *(const float4*)&gvec[col_base + ch*4];
            float4 o;
            o.x = r.x + g.x * v.x;
            o.y = r.y + g.y * v.y;
            o.z = r.z + g.z * v.z;
            o.w = r.w + g.w * v.w;
            *(float4*)&((float*)out)[gidx] = o;
        }
    } else {
        bf16* et = (bf16*)smem;
        #pragma unroll
        for (int m = 0; m < FM; ++m)
            #pragma unroll
            for (int n = 0; n < FN; ++n) {
                int col = wn*(BN/WC) + n*16 + cl;
                float bv = bias[col_base + col];
                #pragma unroll
                for (int j = 0; j < 4; ++j) {
                    int row = wm*(BM/WR) + m*16 + rq*4 + j;
                    float v = acc[m][n][j] + bv;
                    if constexpr (EPI == 2) {        // gelu = v*sigmoid(2u)
                        float u = 0.7978845608028654f * (v + 0.044715f * v * v * v);
                        v = v / (1.f + __expf(-2.f * u));
                    }
                    et[row*(BN+8) + col] = f2bf(v);
                }
            }
        __syncthreads();
        constexpr int CH = BN / 8;
        #pragma unroll
        for (int p = 0; p < (BM*CH)/TPB; ++p) {
            int idx = p * TPB + tid;
            int row = idx / CH, ch = idx % CH;
            bf16x8 v = *(const bf16x8*)&et[row*(BN+8) + ch*8];
            *(bf16x8*)&((bf16*)out)[(size_t)(row_base + row) * N + col_base + ch*8] = v;
        }
    }
}

// ---------------------------------------------------------------------------
// Kernel 4: NATTEN 7x7 — MFMA-tiled (proven R10, unchanged)
// ---------------------------------------------------------------------------
#define QOFF 0
#define KOFF 8192
#define VOFF 36864
#define POFF 65536

__global__ __launch_bounds__(256) void natten_k(const bf16* __restrict__ qkv,
                                                bf16* __restrict__ o)
{
    __shared__ __align__(16) char lds[95232];
    int tid = threadIdx.x;
    int wid = tid >> 6, lane = tid & 63;
    int b = blockIdx.x;
    int h = b % NHD, tile = b / NHD;
    int R0 = (tile >> 3) << 3, C0 = (tile & 7) << 3;
    int wr0 = min(max(R0 - 3, 0), GH - 14);
    int wc0 = min(max(C0 - 3, 0), GW - 14);

    int l8 = lane >> 3, c8 = lane & 7;
    int cs = ((c8 ^ l8) << 3);

    #pragma unroll
    for (int p = 0; p < 2; ++p) {
        int rb = p * 32 + wid * 8;
        int q  = rb + l8;
        int token = (R0 + (q >> 3)) * GW + C0 + (q & 7);
        __builtin_amdgcn_global_load_lds(
            (gptr_t)(const void*)(qkv + (size_t)token * (3*CC) + h * DH + cs),
            (lptr_t)(void*)(lds + QOFF + rb * 128), 16, 0, 0);
    }
    #pragma unroll
    for (int p = 0; p < 7; ++p) {
        int rb = p * 32 + wid * 8;
        int key = rb + l8;
        if (key < 196) {
            int kr = (key * 586) >> 13;
            int kc = key - 14 * kr;
            int token = (wr0 + kr) * GW + wc0 + kc;
            const bf16* base = qkv + (size_t)token * (3*CC) + h * DH + cs;
            __builtin_amdgcn_global_load_lds(
                (gptr_t)(const void*)(base + CC),
                (lptr_t)(void*)(lds + KOFF + rb * 128), 16, 0, 0);
            __builtin_amdgcn_global_load_lds(
                (gptr_t)(const void*)(base + 2*CC),
                (lptr_t)(void*)(lds + VOFF + rb * 128), 16, 0, 0);
        }
    }
    for (int i = tid; i < 896; i += 256)
        *(unsigned int*)(lds + VOFF + 196*128 + i * 4) = 0u;
    for (int i = tid; i < 64*18; i += 256) {
        int row = i / 18, seg = i % 18;
        *(unsigned int*)(lds + POFF + row * 464 + 392 + seg * 4) = 0u;
    }
    __syncthreads();

    int qme = wid * 16 + (lane & 15);
    int qr = R0 + (qme >> 3), qc = C0 + (qme & 7);
    int sh = min(max(qr - 3, 0), GH - KW);
    int sw = min(max(qc - 3, 0), GW - KW);

    bf16x8 bq[2];
    #pragma unroll
    for (int kk = 0; kk < 2; ++kk)
        bq[kk] = *(const bf16x8*)(lds + QOFF + qme * 128 +
                  ((kk * 64 + (lane >> 4) * 16) ^ ((qme & 7) << 4)));

    f32x4 sc[13] = {};
    #pragma unroll
    for (int m = 0; m < 13; ++m) {
        #pragma unroll
        for (int kk = 0; kk < 2; ++kk) {
            int R = m * 16 + (lane & 15);
            bf16x8 af = *(const bf16x8*)(lds + KOFF + R * 128 +
                         ((kk * 64 + (lane >> 4) * 16) ^ ((R & 7) << 4)));
            sc[m] = __builtin_amdgcn_mfma_f32_16x16x32_bf16(af, bq[kk], sc[m], 0, 0, 0);
        }
    }
    float mx = -3e38f;
    #pragma unroll
    for (int m = 0; m < 13; ++m) {
        #pragma unroll
        for (int j = 0; j < 4; ++j) {
            int key = m * 16 + (lane >> 4) * 4 + j;
            int kr = (key * 586) >> 13;
            int kc = key - 14 * kr;
            int kg = wr0 + kr, cg = wc0 + kc;
            bool val = (kg >= sh) && (kg <= sh + 6) && (cg >= sw) && (cg <= sw + 6);
            float s = val ? sc[m][j] * 0.125f : -3e38f;
            sc[m][j] = s;
            mx = fmaxf(mx, s);
        }
    }
    mx = fmaxf(mx, __shfl_xor(mx, 16));
    mx = fmaxf(mx, __shfl_xor(mx, 32));
    float sum = 0.f;
    #pragma unroll
    for (int m = 0; m < 13; ++m)
        #pragma unroll
        for (int j = 0; j < 4; ++j) {
            float e = __expf(sc[m][j] - mx);
            sc[m][j] = e;
            sum += e;
        }
    sum += __shfl_xor(sum, 16);
    sum += __shfl_xor(sum, 32);
    float inv = 1.f / sum;

    #pragma unroll
    for (int m = 0; m < 13; ++m)
        #pragma unroll
        for (int j = 0; j < 4; ++j) {
            int key = m * 16 + (lane >> 4) * 4 + j;
            *(bf16*)(lds + POFF + qme * 464 + key * 2) = f2bf(sc[m][j]);
        }
    asm volatile("s_waitcnt lgkmcnt(0)" ::: "memory");
    __builtin_amdgcn_sched_barrier(0);

    f32x4 oacc[4] = {};
    #pragma unroll
    for (int kk = 0; kk < 7; ++kk) {
        bf16x8 af = *(const bf16x8*)(lds + POFF + qme * 464 + kk * 64 + (lane >> 4) * 16);
        #pragma unroll
        for (int n = 0; n < 4; ++n) {
            int dd = n * 16 + (lane & 15);
            int gch = dd >> 3, dby = (dd & 7) * 2;
            bf16x8 bv;
            #pragma unroll
            for (int j = 0; j < 8; ++j) {
                int key = kk * 32 + (lane >> 4) * 8 + j;
                ((short*)&bv)[j] = *(const short*)(lds + VOFF + key * 128 +
                                    ((gch ^ (key & 7)) << 4) + dby);
            }
            oacc[n] = __builtin_amdgcn_mfma_f32_16x16x32_bf16(af, bv, oacc[n], 0, 0, 0);
        }
    }

    #pragma unroll
    for (int j = 0; j < 4; ++j) {
        int idxq = ((lane >> 4) << 2) + j;
        float iv = __shfl(inv, (lane & 48) | idxq);
        int q2 = wid * 16 + idxq;
        int token = (R0 + (q2 >> 3)) * GW + C0 + (q2 & 7);
        #pragma unroll
        for (int n = 0; n < 4; ++n) {
            int d = n * 16 + (lane & 15);
            o[(size_t)token * CC + h * DH + d] = f2bf(oacc[n][j] * iv);
        }
    }
}

// ---------------------------------------------------------------------------
// launch  (8 dispatches, R12-proven structure)
// ---------------------------------------------------------------------------
extern "C" void kernel_launch(void* const* d_in, const int* in_sizes, int n_in,
                              void* d_out, int out_size, void* d_ws, size_t ws_size,
                              hipStream_t stream)
{
    const float* x      = (const float*)d_in[0];
    const float* cond   = (const float*)d_in[1];
    const float* qkv_w  = (const float*)d_in[2];
    const float* qkv_b  = (const float*)d_in[3];
    const float* proj_w = (const float*)d_in[4];
    const float* proj_b = (const float*)d_in[5];
    const float* fc1_w  = (const float*)d_in[6];
    const float* fc1_b  = (const float*)d_in[7];
    const float* fc2_w  = (const float*)d_in[8];
    const float* fc2_b  = (const float*)d_in[9];
    const float* ada_w  = (const float*)d_in[10];
    const float* ada_b  = (const float*)d_in[11];
    float* out = (float*)d_out;

    char* p = (char*)d_ws;
    float* m       = (float*)p;            p += 6*CC*sizeof(float);
    bf16* y        = (bf16*)p;             p += (size_t)NTOK*CC*2;
    bf16* qkv      = (bf16*)p;             p += (size_t)NTOK*(3*CC)*2;
    bf16* attn_o   = (bf16*)p;             p += (size_t)NTOK*CC*2;
    bf16* hdn      = (bf16*)p;             p += (size_t)NTOK*(4*CC)*2;
    bf16* qkv_wt   = (bf16*)p;             p += (size_t)(3*CC)*CC*2;
    bf16* proj_wt  = (bf16*)p;             p += (size_t)CC*CC*2;
    bf16* fc1_wt   = (bf16*)p;             p += (size_t)(4*CC)*CC*2;
    bf16* fc2_wt   = (bf16*)p;             p += (size_t)CC*(4*CC)*2;

    const float* sh_a = m;
    const float* sc_a = m + CC;
    const float* g_a  = m + 2*CC;
    const float* sh_m = m + 3*CC;
    const float* sc_m = m + 4*CC;
    const float* g_m  = m + 5*CC;

    wt_ada_k<<<468, 256, 0, stream>>>(qkv_w, proj_w, fc1_w, fc2_w,
                                      qkv_wt, proj_wt, fc1_wt, fc2_wt,
                                      cond, ada_w, ada_b, m);
    ln_mod_k<<<NTOK/2, 256, 0, stream>>>(x, sh_a, sc_a, y);
    // qkv: 64x128 tile, grid (9,64)=576 blocks
    mgemm_k<0, bf16, 64, 128, 256, 2><<<dim3((3*CC)/128, NTOK/64), 256, 0, stream>>>(
        y, qkv_wt, qkv_b, nullptr, nullptr, qkv, NTOK, 3*CC, CC);
    natten_k<<<(NTOK/64)*NHD, 256, 0, stream>>>(qkv, attn_o);
    // proj: 32x64 tile, depth 3, grid (6,128)=768 blocks
    mgemm_k<1, float, 32, 64, 256, 3><<<dim3(CC/64, NTOK/32), 256, 0, stream>>>(
        attn_o, proj_wt, proj_b, x, g_a, out, NTOK, CC, CC);
    ln_mod_k<<<NTOK/2, 256, 0, stream>>>(out, sh_m, sc_m, y);
    // fc1: 64x128 tile, grid (12,64)=768 blocks
    mgemm_k<2, bf16, 64, 128, 256, 2><<<dim3((4*CC)/128, NTOK/64), 256, 0, stream>>>(
        y, fc1_wt, fc1_b, nullptr, nullptr, hdn, NTOK, 4*CC, CC);
    // fc2: 32x64 tile, depth 3, grid (6,128)=768 blocks, 24 k-iters
    mgemm_k<1, float, 32, 64, 256, 3><<<dim3(CC/64, NTOK/32), 256, 0, stream>>>(
        hdn, fc2_wt, fc2_b, out, g_m, out, NTOK, CC, 4*CC);
}